// Round 1
// baseline (779.978 us; speedup 1.0000x reference)
//
#include <hip/hip_runtime.h>
#include <math.h>

#define BN    16
#define NGTC  32
#define NBUCK 32768
#define BLK   256

struct Accum {
  unsigned int npos[BN];
  float pos_sum;
  float box_sum;
  float sum_hi[BN];
  float sum_bd[BN];
  int   t_bucket[BN];
  unsigned int r_need[BN];
  unsigned long long best[BN][NGTC];
};

__device__ inline float wred_sum_f(float v) {
#pragma unroll
  for (int o = 32; o > 0; o >>= 1) v += __shfl_down(v, o, 64);
  return v;
}
__device__ inline unsigned wred_sum_u(unsigned v) {
#pragma unroll
  for (int o = 32; o > 0; o >>= 1) v += __shfl_down(v, o, 64);
  return v;
}
__device__ inline unsigned long long wred_max_u64(unsigned long long v) {
#pragma unroll
  for (int o = 32; o > 0; o >>= 1) {
    unsigned long long w = __shfl_down(v, o, 64);
    v = (w > v) ? w : v;
  }
  return v;
}
__device__ inline float sl1(float d) {
  float ad = fabsf(d);
  return ad < 1.f ? 0.5f * d * d : ad - 0.5f;
}

// Pass 1: per-(b,gt) best anchor = argmax_a IoU, first occurrence on ties.
__global__ __launch_bounds__(BLK) void k_match(const float4* __restrict__ anchors,
                                               const float4* __restrict__ gt,
                                               Accum* __restrict__ acc, int A) {
  __shared__ float4 sgt[NGTC];
  __shared__ float  sarea[NGTC];
  int b = blockIdx.y;
  int a = blockIdx.x * BLK + threadIdx.x;
  if (threadIdx.x < NGTC) {
    float4 g = gt[b * NGTC + threadIdx.x];
    sgt[threadIdx.x] = g;
    sarea[threadIdx.x] = (g.z - g.x) * (g.w - g.y);
  }
  __syncthreads();
  bool valid = a < A;
  float4 av = valid ? anchors[a] : make_float4(0.f, 0.f, 0.f, 0.f);
  float area_a = (av.z - av.x) * (av.w - av.y);
  int lane = threadIdx.x & 63;
#pragma unroll 4
  for (int j = 0; j < NGTC; ++j) {
    float4 g = sgt[j];
    float w = fminf(av.z, g.z) - fmaxf(av.x, g.x);
    float h = fminf(av.w, g.w) - fmaxf(av.y, g.y);
    w = fmaxf(w, 0.f); h = fmaxf(h, 0.f);
    float inter = w * h;
    float iou = inter / (area_a + sarea[j] - inter);
    unsigned long long key = valid
        ? ((((unsigned long long)__float_as_uint(iou)) << 32) | (unsigned)(~(unsigned)a))
        : 0ull;
    key = wred_max_u64(key);
    if (lane == 0) atomicMax(&acc->best[b][j], key);
  }
}

// Pass 2: recompute per-anchor max IoU + argmax, apply forced matches,
// accumulate n_pos / pos BCE / box smooth-L1, store negative BCE + histogram.
__global__ __launch_bounds__(BLK) void k_main(const float* __restrict__ labels,
                                              const float4* __restrict__ poffs,
                                              const float4* __restrict__ anchors,
                                              const float4* __restrict__ gt,
                                              Accum* __restrict__ acc,
                                              unsigned int* __restrict__ hist,
                                              float* __restrict__ neg, int A) {
  __shared__ float4 sgt[NGTC];
  __shared__ float  sarea[NGTC];
  __shared__ unsigned sbest[NGTC];
  __shared__ float sredf[BLK / 64];
  __shared__ float sredb[BLK / 64];
  __shared__ unsigned sredu[BLK / 64];
  int b = blockIdx.y;
  int a = blockIdx.x * BLK + threadIdx.x;
  if (threadIdx.x < NGTC) {
    float4 g = gt[b * NGTC + threadIdx.x];
    sgt[threadIdx.x] = g;
    sarea[threadIdx.x] = (g.z - g.x) * (g.w - g.y);
    sbest[threadIdx.x] = ~(unsigned)(acc->best[b][threadIdx.x] & 0xFFFFFFFFull);
  }
  __syncthreads();
  bool valid = a < A;
  float4 av = valid ? anchors[a] : make_float4(0.f, 0.f, 0.f, 0.f);
  float area_a = (av.z - av.x) * (av.w - av.y);
  float best_iou = -1.f;
  int gid = 0;
#pragma unroll 4
  for (int j = 0; j < NGTC; ++j) {
    float4 g = sgt[j];
    float w = fminf(av.z, g.z) - fmaxf(av.x, g.x);
    float h = fminf(av.w, g.w) - fmaxf(av.y, g.y);
    w = fmaxf(w, 0.f); h = fmaxf(h, 0.f);
    float inter = w * h;
    float iou = inter / (area_a + sarea[j] - inter);
    if (iou > best_iou) { best_iou = iou; gid = j; }
  }
  bool forced = false;
#pragma unroll
  for (int j = 0; j < NGTC; ++j)
    if (sbest[j] == (unsigned)a) { gid = j; forced = true; }  // ascending = last wins
  bool pos = valid && (forced || best_iou > 0.3f);
  float x = valid ? labels[(size_t)b * A + a] : 0.f;
  float bce = fmaxf(x, 0.f) - (pos ? x : 0.f) + log1pf(expf(-fabsf(x)));
  float boxc = 0.f;
  if (pos) {
    float4 g = sgt[gid];
    float4 p = poffs[(size_t)b * A + a];
    float acx = (av.x + av.z) * 0.5f, acy = (av.y + av.w) * 0.5f;
    float aw = av.z - av.x, ah = av.w - av.y;
    float gcx = (g.x + g.z) * 0.5f, gcy = (g.y + g.w) * 0.5f;
    float gw = g.z - g.x, gh = g.w - g.y;
    float t0 = (gcx - acx) / (aw / 10.f);
    float t1 = (gcy - acy) / (ah / 10.f);
    float t2 = logf(gw / aw) * 5.f;
    float t3 = logf(gh / ah) * 5.f;
    boxc = sl1(p.x - t0) + sl1(p.y - t1) + sl1(p.z - t2) + sl1(p.w - t3);
  }
  if (valid) {
    size_t idx = (size_t)b * A + a;
    if (pos) {
      neg[idx] = -1.f;
    } else {
      neg[idx] = bce;
      atomicAdd(&hist[b * NBUCK + (__float_as_uint(bce) >> 16)], 1u);
    }
  }
  float psum = pos ? bce : 0.f;
  unsigned cnt = pos ? 1u : 0u;
  psum = wred_sum_f(psum);
  float bsum = wred_sum_f(boxc);
  cnt = wred_sum_u(cnt);
  int wid = threadIdx.x >> 6;
  int lane = threadIdx.x & 63;
  if (lane == 0) { sredf[wid] = psum; sredb[wid] = bsum; sredu[wid] = cnt; }
  __syncthreads();
  if (threadIdx.x == 0) {
    float ps = 0.f, bs = 0.f; unsigned c = 0;
#pragma unroll
    for (int w = 0; w < BLK / 64; ++w) { ps += sredf[w]; bs += sredb[w]; c += sredu[w]; }
    if (c) atomicAdd(&acc->npos[b], c);
    atomicAdd(&acc->pos_sum, ps);
    atomicAdd(&acc->box_sum, bs);
  }
}

// Pass 3: per-row find boundary bucket for top-(3*n_pos) negatives.
__global__ __launch_bounds__(128) void k_thresh(Accum* __restrict__ acc,
                                                const unsigned int* __restrict__ hist) {
  int b = blockIdx.x;
  __shared__ unsigned ccnt[128];
  const unsigned* h = hist + b * NBUCK;
  unsigned s = 0;
  int base = threadIdx.x * 256;
  for (int i = 0; i < 256; ++i) s += h[base + i];
  ccnt[threadIdx.x] = s;
  __syncthreads();
  if (threadIdx.x == 0) {
    unsigned long long k = 3ull * (unsigned long long)acc->npos[b];
    unsigned long long cum = 0;
    int cb = -1;
    for (int c = 127; c >= 0; --c) {
      if (cum + ccnt[c] >= k) { cb = c; break; }
      cum += ccnt[c];
    }
    int tb = -1; unsigned r = 0;
    if (cb >= 0) {
      for (int u = 255; u >= 0; --u) {
        int bk = cb * 256 + u;
        unsigned c = h[bk];
        if (cum + c >= k) { tb = bk; r = (unsigned)(k - cum); break; }
        cum += c;
      }
    }
    acc->t_bucket[b] = tb;   // -1 => take everything
    acc->r_need[b] = r;
  }
}

// Pass 4: sum negatives above boundary bucket exactly; boundary bucket separately.
__global__ __launch_bounds__(BLK) void k_negsum(const float* __restrict__ neg,
                                                Accum* __restrict__ acc, int A) {
  __shared__ float sh[BLK / 64];
  __shared__ float sb[BLK / 64];
  int b = blockIdx.y;
  int a = blockIdx.x * BLK + threadIdx.x;
  int tb = acc->t_bucket[b];
  float hi = 0.f, bd = 0.f;
  if (a < A) {
    float v = neg[(size_t)b * A + a];
    if (v >= 0.f) {
      int bk = (int)(__float_as_uint(v) >> 16);
      if (bk > tb) hi = v;
      else if (bk == tb) bd = v;
    }
  }
  hi = wred_sum_f(hi);
  bd = wred_sum_f(bd);
  int wid = threadIdx.x >> 6;
  int lane = threadIdx.x & 63;
  if (lane == 0) { sh[wid] = hi; sb[wid] = bd; }
  __syncthreads();
  if (threadIdx.x == 0) {
    float h = 0.f, d = 0.f;
#pragma unroll
    for (int w = 0; w < BLK / 64; ++w) { h += sh[w]; d += sb[w]; }
    atomicAdd(&acc->sum_hi[b], h);
    atomicAdd(&acc->sum_bd[b], d);
  }
}

__global__ void k_final(const Accum* __restrict__ acc,
                        const unsigned int* __restrict__ hist,
                        float* __restrict__ out) {
  if (threadIdx.x == 0 && blockIdx.x == 0) {
    unsigned int npt = 0;
    for (int b = 0; b < BN; ++b) npt += acc->npos[b];
    float hard = 0.f;
    for (int b = 0; b < BN; ++b) {
      hard += acc->sum_hi[b];
      unsigned r = acc->r_need[b];
      if (r) {
        int tb = acc->t_bucket[b];
        unsigned c = hist[b * NBUCK + tb];
        if (c) hard += acc->sum_bd[b] * ((float)r / (float)c);
      }
    }
    float npf = (float)npt;
    float box = acc->box_sum / (npf * 4.f);
    float cls = (hard + acc->pos_sum) / npf;
    out[0] = box + cls;
    out[1] = box;
    out[2] = cls;
  }
}

extern "C" void kernel_launch(void* const* d_in, const int* in_sizes, int n_in,
                              void* d_out, int out_size, void* d_ws, size_t ws_size,
                              hipStream_t stream) {
  const float*  labels  = (const float*)d_in[0];
  const float4* poffs   = (const float4*)d_in[1];
  const float4* anchors = (const float4*)d_in[2];
  const float4* gt      = (const float4*)d_in[3];
  int A = in_sizes[2] / 4;  // 100000

  char* ws = (char*)d_ws;
  Accum* acc = (Accum*)ws;
  size_t off_hist = (sizeof(Accum) + 255) & ~(size_t)255;
  unsigned int* hist = (unsigned int*)(ws + off_hist);
  size_t off_neg = off_hist + (size_t)BN * NBUCK * sizeof(unsigned int);
  float* neg = (float*)(ws + off_neg);

  hipMemsetAsync(ws, 0, off_neg, stream);

  dim3 grid((A + BLK - 1) / BLK, BN);
  k_match<<<grid, BLK, 0, stream>>>(anchors, gt, acc, A);
  k_main<<<grid, BLK, 0, stream>>>(labels, poffs, anchors, gt, acc, hist, neg, A);
  k_thresh<<<BN, 128, 0, stream>>>(acc, hist);
  k_negsum<<<grid, BLK, 0, stream>>>(neg, acc, A);
  k_final<<<1, 64, 0, stream>>>(acc, hist, (float*)d_out);
}

// Round 2
// 397.397 us; speedup vs baseline: 1.9627x; 1.9627x over previous
//
#include <hip/hip_runtime.h>
#include <math.h>

#define BN    16
#define NGTC  32
#define NBUCK 32768
#define BLK   256
#define MITER 4

struct Accum {
  unsigned int npos[BN];
  float pos_sum;
  float box_sum;
  float sum_hi[BN];
  float sum_bd[BN];
  int   t_bucket[BN];
  unsigned int r_need[BN];
  unsigned long long best[BN][NGTC];
};

__device__ inline float wred_sum_f(float v) {
#pragma unroll
  for (int o = 32; o > 0; o >>= 1) v += __shfl_down(v, o, 64);
  return v;
}
__device__ inline unsigned wred_sum_u(unsigned v) {
#pragma unroll
  for (int o = 32; o > 0; o >>= 1) v += __shfl_down(v, o, 64);
  return v;
}
__device__ inline float sl1(float d) {
  float ad = fabsf(d);
  return ad < 1.f ? 0.5f * d * d : ad - 0.5f;
}

// Pass 1: per-block partial argmax of IoU per (b,gt), via LDS atomicMax.
// key = (iou_bits << 32) | ~anchor_idx  -> max == (max iou, lowest idx on tie).
__global__ __launch_bounds__(BLK) void k_match(const float4* __restrict__ anchors,
                                               const float4* __restrict__ gt,
                                               unsigned long long* __restrict__ partial,
                                               int A, int nbx) {
  __shared__ unsigned long long sbest[NGTC];
  __shared__ float4 sgt[NGTC];
  __shared__ float  sarea[NGTC];
  int b = blockIdx.y;
  int t = threadIdx.x;
  if (t < NGTC) {
    float4 g = gt[b * NGTC + t];
    sgt[t] = g;
    sarea[t] = (g.z - g.x) * (g.w - g.y);
    sbest[t] = 0ull;
  }
  __syncthreads();
  int rot = t & 31;
#pragma unroll
  for (int it = 0; it < MITER; ++it) {
    int a = (blockIdx.x * MITER + it) * BLK + t;
    if (a < A) {
      float4 av = anchors[a];
      float area_a = (av.z - av.x) * (av.w - av.y);
#pragma unroll
      for (int jj = 0; jj < NGTC; ++jj) {
        int j = (jj + rot) & 31;  // stagger lanes across the 32 LDS slots
        float4 g = sgt[j];
        float w = fminf(av.z, g.z) - fmaxf(av.x, g.x);
        float h = fminf(av.w, g.w) - fmaxf(av.y, g.y);
        w = fmaxf(w, 0.f); h = fmaxf(h, 0.f);
        float inter = w * h;
        if (inter > 0.f) {
          float iou = inter / (area_a + sarea[j] - inter);
          unsigned long long key =
              (((unsigned long long)__float_as_uint(iou)) << 32) |
              (unsigned)(~(unsigned)a);
          atomicMax(&sbest[j], key);
        }
      }
    }
  }
  __syncthreads();
  if (t < NGTC)
    partial[((size_t)b * NGTC + t) * nbx + blockIdx.x] = sbest[t];
}

// Pass 1b: reduce partials -> acc->best[b][j]. One thread per (b,gt).
__global__ __launch_bounds__(512) void k_match2(const unsigned long long* __restrict__ partial,
                                                Accum* __restrict__ acc, int nbx) {
  int t = threadIdx.x;            // 0..511
  int b = t >> 5, j = t & 31;
  const unsigned long long* p = partial + ((size_t)b * NGTC + j) * nbx;
  unsigned long long best = 0ull;
  for (int i = 0; i < nbx; ++i) {
    unsigned long long v = p[i];
    best = v > best ? v : best;
  }
  if (best == 0ull) best = 0xFFFFFFFFull;  // no overlap anywhere -> argmax = anchor 0
  acc->best[b][j] = best;
}

// Pass 2: recompute per-anchor max IoU + argmax, apply forced matches,
// accumulate n_pos / pos BCE / box smooth-L1, store negative BCE + histogram.
__global__ __launch_bounds__(BLK) void k_main(const float* __restrict__ labels,
                                              const float4* __restrict__ poffs,
                                              const float4* __restrict__ anchors,
                                              const float4* __restrict__ gt,
                                              Accum* __restrict__ acc,
                                              unsigned int* __restrict__ hist,
                                              float* __restrict__ neg, int A) {
  __shared__ float4 sgt[NGTC];
  __shared__ float  sarea[NGTC];
  __shared__ unsigned sbest[NGTC];
  __shared__ float sredf[BLK / 64];
  __shared__ float sredb[BLK / 64];
  __shared__ unsigned sredu[BLK / 64];
  int b = blockIdx.y;
  int a = blockIdx.x * BLK + threadIdx.x;
  if (threadIdx.x < NGTC) {
    float4 g = gt[b * NGTC + threadIdx.x];
    sgt[threadIdx.x] = g;
    sarea[threadIdx.x] = (g.z - g.x) * (g.w - g.y);
    sbest[threadIdx.x] = ~(unsigned)(acc->best[b][threadIdx.x] & 0xFFFFFFFFull);
  }
  __syncthreads();
  bool valid = a < A;
  float4 av = valid ? anchors[a] : make_float4(0.f, 0.f, 0.f, 0.f);
  float area_a = (av.z - av.x) * (av.w - av.y);
  float best_iou = -1.f;
  int gid = 0;
#pragma unroll 4
  for (int j = 0; j < NGTC; ++j) {
    float4 g = sgt[j];
    float w = fminf(av.z, g.z) - fmaxf(av.x, g.x);
    float h = fminf(av.w, g.w) - fmaxf(av.y, g.y);
    w = fmaxf(w, 0.f); h = fmaxf(h, 0.f);
    float inter = w * h;
    float iou = inter / (area_a + sarea[j] - inter);
    if (iou > best_iou) { best_iou = iou; gid = j; }
  }
  bool forced = false;
#pragma unroll
  for (int j = 0; j < NGTC; ++j)
    if (sbest[j] == (unsigned)a) { gid = j; forced = true; }  // ascending = last wins
  bool pos = valid && (forced || best_iou > 0.3f);
  float x = valid ? labels[(size_t)b * A + a] : 0.f;
  float bce = fmaxf(x, 0.f) - (pos ? x : 0.f) + log1pf(expf(-fabsf(x)));
  float boxc = 0.f;
  if (pos) {
    float4 g = sgt[gid];
    float4 p = poffs[(size_t)b * A + a];
    float acx = (av.x + av.z) * 0.5f, acy = (av.y + av.w) * 0.5f;
    float aw = av.z - av.x, ah = av.w - av.y;
    float gcx = (g.x + g.z) * 0.5f, gcy = (g.y + g.w) * 0.5f;
    float gw = g.z - g.x, gh = g.w - g.y;
    float t0 = (gcx - acx) / (aw / 10.f);
    float t1 = (gcy - acy) / (ah / 10.f);
    float t2 = logf(gw / aw) * 5.f;
    float t3 = logf(gh / ah) * 5.f;
    boxc = sl1(p.x - t0) + sl1(p.y - t1) + sl1(p.z - t2) + sl1(p.w - t3);
  }
  if (valid) {
    size_t idx = (size_t)b * A + a;
    if (pos) {
      neg[idx] = -1.f;
    } else {
      neg[idx] = bce;
      atomicAdd(&hist[b * NBUCK + (__float_as_uint(bce) >> 16)], 1u);
    }
  }
  float psum = pos ? bce : 0.f;
  unsigned cnt = pos ? 1u : 0u;
  psum = wred_sum_f(psum);
  float bsum = wred_sum_f(boxc);
  cnt = wred_sum_u(cnt);
  int wid = threadIdx.x >> 6;
  int lane = threadIdx.x & 63;
  if (lane == 0) { sredf[wid] = psum; sredb[wid] = bsum; sredu[wid] = cnt; }
  __syncthreads();
  if (threadIdx.x == 0) {
    float ps = 0.f, bs = 0.f; unsigned c = 0;
#pragma unroll
    for (int w = 0; w < BLK / 64; ++w) { ps += sredf[w]; bs += sredb[w]; c += sredu[w]; }
    if (c) atomicAdd(&acc->npos[b], c);
    atomicAdd(&acc->pos_sum, ps);
    atomicAdd(&acc->box_sum, bs);
  }
}

// Pass 3: per-row find boundary bucket for top-(3*n_pos) negatives.
__global__ __launch_bounds__(128) void k_thresh(Accum* __restrict__ acc,
                                                const unsigned int* __restrict__ hist) {
  int b = blockIdx.x;
  __shared__ unsigned ccnt[128];
  const unsigned* h = hist + b * NBUCK;
  unsigned s = 0;
  int base = threadIdx.x * 256;
  for (int i = 0; i < 256; ++i) s += h[base + i];
  ccnt[threadIdx.x] = s;
  __syncthreads();
  if (threadIdx.x == 0) {
    unsigned long long k = 3ull * (unsigned long long)acc->npos[b];
    unsigned long long cum = 0;
    int cb = -1;
    for (int c = 127; c >= 0; --c) {
      if (cum + ccnt[c] >= k) { cb = c; break; }
      cum += ccnt[c];
    }
    int tb = -1; unsigned r = 0;
    if (cb >= 0) {
      for (int u = 255; u >= 0; --u) {
        int bk = cb * 256 + u;
        unsigned c = h[bk];
        if (cum + c >= k) { tb = bk; r = (unsigned)(k - cum); break; }
        cum += c;
      }
    }
    acc->t_bucket[b] = tb;   // -1 => take everything
    acc->r_need[b] = r;
  }
}

// Pass 4: sum negatives above boundary bucket exactly; boundary bucket separately.
__global__ __launch_bounds__(BLK) void k_negsum(const float* __restrict__ neg,
                                                Accum* __restrict__ acc, int A) {
  __shared__ float sh[BLK / 64];
  __shared__ float sb[BLK / 64];
  int b = blockIdx.y;
  int a = blockIdx.x * BLK + threadIdx.x;
  int tb = acc->t_bucket[b];
  float hi = 0.f, bd = 0.f;
  if (a < A) {
    float v = neg[(size_t)b * A + a];
    if (v >= 0.f) {
      int bk = (int)(__float_as_uint(v) >> 16);
      if (bk > tb) hi = v;
      else if (bk == tb) bd = v;
    }
  }
  hi = wred_sum_f(hi);
  bd = wred_sum_f(bd);
  int wid = threadIdx.x >> 6;
  int lane = threadIdx.x & 63;
  if (lane == 0) { sh[wid] = hi; sb[wid] = bd; }
  __syncthreads();
  if (threadIdx.x == 0) {
    float h = 0.f, d = 0.f;
#pragma unroll
    for (int w = 0; w < BLK / 64; ++w) { h += sh[w]; d += sb[w]; }
    atomicAdd(&acc->sum_hi[b], h);
    atomicAdd(&acc->sum_bd[b], d);
  }
}

__global__ void k_final(const Accum* __restrict__ acc,
                        const unsigned int* __restrict__ hist,
                        float* __restrict__ out) {
  if (threadIdx.x == 0 && blockIdx.x == 0) {
    unsigned int npt = 0;
    for (int b = 0; b < BN; ++b) npt += acc->npos[b];
    float hard = 0.f;
    for (int b = 0; b < BN; ++b) {
      hard += acc->sum_hi[b];
      unsigned r = acc->r_need[b];
      if (r) {
        int tb = acc->t_bucket[b];
        unsigned c = hist[b * NBUCK + tb];
        if (c) hard += acc->sum_bd[b] * ((float)r / (float)c);
      }
    }
    float npf = (float)npt;
    float box = acc->box_sum / (npf * 4.f);
    float cls = (hard + acc->pos_sum) / npf;
    out[0] = box + cls;
    out[1] = box;
    out[2] = cls;
  }
}

extern "C" void kernel_launch(void* const* d_in, const int* in_sizes, int n_in,
                              void* d_out, int out_size, void* d_ws, size_t ws_size,
                              hipStream_t stream) {
  const float*  labels  = (const float*)d_in[0];
  const float4* poffs   = (const float4*)d_in[1];
  const float4* anchors = (const float4*)d_in[2];
  const float4* gt      = (const float4*)d_in[3];
  int A = in_sizes[2] / 4;  // 100000

  char* ws = (char*)d_ws;
  Accum* acc = (Accum*)ws;
  size_t off_hist = (sizeof(Accum) + 255) & ~(size_t)255;
  unsigned int* hist = (unsigned int*)(ws + off_hist);
  size_t off_neg = off_hist + (size_t)BN * NBUCK * sizeof(unsigned int);
  float* neg = (float*)(ws + off_neg);
  // partial[] aliases the neg[] region: partial is fully consumed by k_match2
  // before k_main writes neg (stream-ordered), so the lifetimes are disjoint.
  unsigned long long* partial = (unsigned long long*)(ws + off_neg);

  hipMemsetAsync(ws, 0, off_neg, stream);

  int nbx = (A + BLK * MITER - 1) / (BLK * MITER);   // 98
  dim3 mgrid(nbx, BN);
  k_match<<<mgrid, BLK, 0, stream>>>(anchors, gt, partial, A, nbx);
  k_match2<<<1, 512, 0, stream>>>(partial, acc, nbx);

  dim3 grid((A + BLK - 1) / BLK, BN);
  k_main<<<grid, BLK, 0, stream>>>(labels, poffs, anchors, gt, acc, hist, neg, A);
  k_thresh<<<BN, 128, 0, stream>>>(acc, hist);
  k_negsum<<<grid, BLK, 0, stream>>>(neg, acc, A);
  k_final<<<1, 64, 0, stream>>>(acc, hist, (float*)d_out);
}

// Round 3
// 154.160 us; speedup vs baseline: 5.0595x; 2.5778x over previous
//
#include <hip/hip_runtime.h>
#include <math.h>

#define BN    16
#define NGTC  32
#define NB    8192      // 13-bit value buckets: float_bits >> 19
#define BSH   19
#define BLK   256
#define MITER 4
#define GX    32        // k_main blocks per batch row

struct Accum {
  unsigned int npos[BN];
  float pos_sum;
  float box_sum;
  float hard[BN];
  unsigned long long best[BN][NGTC];
};

__device__ inline float wred_sum_f(float v) {
#pragma unroll
  for (int o = 32; o > 0; o >>= 1) v += __shfl_down(v, o, 64);
  return v;
}
__device__ inline unsigned wred_sum_u(unsigned v) {
#pragma unroll
  for (int o = 32; o > 0; o >>= 1) v += __shfl_down(v, o, 64);
  return v;
}
__device__ inline float sl1(float d) {
  float ad = fabsf(d);
  return ad < 1.f ? 0.5f * d * d : ad - 0.5f;
}

// Pass 1: per-block partial argmax of IoU per (b,gt), via LDS atomicMax.
// key = (iou_bits << 32) | ~anchor_idx  -> max == (max iou, lowest idx on tie).
__global__ __launch_bounds__(BLK) void k_match(const float4* __restrict__ anchors,
                                               const float4* __restrict__ gt,
                                               unsigned long long* __restrict__ partial,
                                               int A) {
  __shared__ unsigned long long sbest[NGTC];
  __shared__ float4 sgt[NGTC];
  __shared__ float  sarea[NGTC];
  int b = blockIdx.y;
  int t = threadIdx.x;
  if (t < NGTC) {
    float4 g = gt[b * NGTC + t];
    sgt[t] = g;
    sarea[t] = (g.z - g.x) * (g.w - g.y);
    sbest[t] = 0ull;
  }
  __syncthreads();
  int rot = t & 31;
#pragma unroll
  for (int it = 0; it < MITER; ++it) {
    int a = (blockIdx.x * MITER + it) * BLK + t;
    if (a < A) {
      float4 av = anchors[a];
      float area_a = (av.z - av.x) * (av.w - av.y);
#pragma unroll
      for (int jj = 0; jj < NGTC; ++jj) {
        int j = (jj + rot) & 31;  // stagger lanes across the 32 LDS slots
        float4 g = sgt[j];
        float w = fminf(av.z, g.z) - fmaxf(av.x, g.x);
        float h = fminf(av.w, g.w) - fmaxf(av.y, g.y);
        w = fmaxf(w, 0.f); h = fmaxf(h, 0.f);
        float inter = w * h;
        if (inter > 0.f) {
          float iou = inter / (area_a + sarea[j] - inter);
          unsigned long long key =
              (((unsigned long long)__float_as_uint(iou)) << 32) |
              (unsigned)(~(unsigned)a);
          atomicMax(&sbest[j], key);
        }
      }
    }
  }
  __syncthreads();
  // transposed layout: block-major, (b,j)-minor -> k_match2 reads coalesced
  if (t < NGTC)
    partial[(size_t)blockIdx.x * (BN * NGTC) + b * NGTC + t] = sbest[t];
}

// Pass 1b: reduce partials -> acc->best[b][j]. One thread per (b,gt), coalesced.
__global__ __launch_bounds__(512) void k_match2(const unsigned long long* __restrict__ partial,
                                                Accum* __restrict__ acc, int nbx) {
  int t = threadIdx.x;            // 0..511
  int b = t >> 5, j = t & 31;
  unsigned long long best = 0ull;
  for (int i = 0; i < nbx; ++i) {
    unsigned long long v = partial[(size_t)i * (BN * NGTC) + t];
    best = v > best ? v : best;
  }
  if (best == 0ull) best = 0xFFFFFFFFull;  // no overlap anywhere -> argmax = anchor 0
  acc->best[b][j] = best;
}

// Pass 2: per-anchor argmax (division-free), forced matches, pos BCE / box loss,
// and per-block LDS count+sum histograms of negative BCE, merged to global.
__global__ __launch_bounds__(BLK) void k_main(const float* __restrict__ labels,
                                              const float4* __restrict__ poffs,
                                              const float4* __restrict__ anchors,
                                              const float4* __restrict__ gt,
                                              Accum* __restrict__ acc,
                                              unsigned int* __restrict__ ghc,
                                              float* __restrict__ ghs, int A) {
  __shared__ unsigned int hc[NB];
  __shared__ float        hs[NB];
  __shared__ float4 sgt[NGTC];
  __shared__ float  sarea[NGTC];
  __shared__ unsigned sbest[NGTC];
  __shared__ float sredf[BLK / 64];
  __shared__ float sredb[BLK / 64];
  __shared__ unsigned sredu[BLK / 64];
  int b = blockIdx.y;
  int t = threadIdx.x;
  for (int i = t; i < NB; i += BLK) { hc[i] = 0u; hs[i] = 0.f; }
  if (t < NGTC) {
    float4 g = gt[b * NGTC + t];
    sgt[t] = g;
    sarea[t] = (g.z - g.x) * (g.w - g.y);
    sbest[t] = ~(unsigned)(acc->best[b][t] & 0xFFFFFFFFull);
  }
  __syncthreads();

  float psum = 0.f, bsum = 0.f;
  unsigned cnt = 0u;
  for (int a = blockIdx.x * BLK + t; a < A; a += GX * BLK) {
    float4 av = anchors[a];
    float area_a = (av.z - av.x) * (av.w - av.y);
    float bn = -1.f, bd = 1.f;   // best inter / best denom (iou = bn/bd)
    int gid = 0;
#pragma unroll
    for (int j = 0; j < NGTC; ++j) {
      float4 g = sgt[j];
      float w = fminf(av.z, g.z) - fmaxf(av.x, g.x);
      float h = fminf(av.w, g.w) - fmaxf(av.y, g.y);
      w = fmaxf(w, 0.f); h = fmaxf(h, 0.f);
      float inter = w * h;
      float dj = area_a + sarea[j] - inter;
      if (inter * bd > bn * dj) { bn = inter; bd = dj; gid = j; }
    }
    bool forced = false;
#pragma unroll
    for (int j = 0; j < NGTC; ++j)
      if (sbest[j] == (unsigned)a) { gid = j; forced = true; }  // ascending = last wins
    bool pos = forced || (bn > 0.3f * bd);
    float x = labels[(size_t)b * A + a];
    float e = __expf(-fabsf(x));
    float sp = fmaxf(x, 0.f) + __logf(1.f + e);   // softplus = bce(y=0)
    if (pos) {
      float bce = sp - x;                          // bce(y=1)
      cnt++; psum += bce;
      float4 g = sgt[gid];
      float4 p = poffs[(size_t)b * A + a];
      float acx = (av.x + av.z) * 0.5f, acy = (av.y + av.w) * 0.5f;
      float aw = av.z - av.x, ah = av.w - av.y;
      float gcx = (g.x + g.z) * 0.5f, gcy = (g.y + g.w) * 0.5f;
      float gw = g.z - g.x, gh = g.w - g.y;
      float t0 = (gcx - acx) / (aw / 10.f);
      float t1 = (gcy - acy) / (ah / 10.f);
      float t2 = __logf(gw / aw) * 5.f;
      float t3 = __logf(gh / ah) * 5.f;
      bsum += sl1(p.x - t0) + sl1(p.y - t1) + sl1(p.z - t2) + sl1(p.w - t3);
    } else {
      unsigned bk = __float_as_uint(sp) >> BSH;
      atomicAdd(&hc[bk], 1u);
      atomicAdd(&hs[bk], sp);
    }
  }

  psum = wred_sum_f(psum);
  bsum = wred_sum_f(bsum);
  cnt  = wred_sum_u(cnt);
  int wid = t >> 6, lane = t & 63;
  if (lane == 0) { sredf[wid] = psum; sredb[wid] = bsum; sredu[wid] = cnt; }
  __syncthreads();
  if (t == 0) {
    float ps = 0.f, bs = 0.f; unsigned c = 0;
#pragma unroll
    for (int w = 0; w < BLK / 64; ++w) { ps += sredf[w]; bs += sredb[w]; c += sredu[w]; }
    if (c) atomicAdd(&acc->npos[b], c);
    atomicAdd(&acc->pos_sum, ps);
    atomicAdd(&acc->box_sum, bs);
  }
  // merge nonzero buckets to global histogram
  for (int i = t; i < NB; i += BLK) {
    unsigned c = hc[i];
    if (c) {
      atomicAdd(&ghc[b * NB + i], c);
      atomicAdd(&ghs[b * NB + i], hs[i]);
    }
  }
}

// Pass 3: per-row suffix-select top-(3*n_pos) from count+sum histograms.
__global__ __launch_bounds__(BLK) void k_sel(Accum* __restrict__ acc,
                                             const unsigned int* __restrict__ ghc,
                                             const float* __restrict__ ghs) {
  int b = blockIdx.x, t = threadIdx.x;
  __shared__ unsigned cc[BLK];
  __shared__ float    cs[BLK];
  const unsigned* c = ghc + (size_t)b * NB;
  const float*    s = ghs + (size_t)b * NB;
  const int CH = NB / BLK;   // 32 buckets per thread-chunk
  unsigned cm = 0; float sm = 0.f;
  int base = t * CH;
  for (int i = 0; i < CH; ++i) { cm += c[base + i]; sm += s[base + i]; }
  cc[t] = cm; cs[t] = sm;
  __syncthreads();
  if (t == 0) {
    unsigned k = 3u * acc->npos[b];
    unsigned cum = 0; float hard = 0.f; int cb = -1;
    for (int q = BLK - 1; q >= 0; --q) {
      if (cum + cc[q] >= k) { cb = q; break; }
      cum += cc[q]; hard += cs[q];
    }
    if (cb >= 0) {
      for (int u = CH - 1; u >= 0; --u) {
        int bk = cb * CH + u;
        unsigned c2 = c[bk];
        if (cum + c2 >= k) {
          unsigned r = k - cum;
          if (c2 && r) {
            float m  = s[bk] / (float)c2;
            float lo = __uint_as_float((unsigned)bk << BSH);
            float hi = __uint_as_float((unsigned)(bk + 1) << BSH);
            // uniform-within-bucket model for top-r sum; exact at r==c2
            hard += (float)r * m +
                    (float)r * (float)(c2 - r) * (hi - lo) / (2.f * (float)c2);
          }
          break;
        }
        cum += c2; hard += s[bk];
      }
    }
    acc->hard[b] = hard;
  }
}

__global__ void k_final(const Accum* __restrict__ acc, float* __restrict__ out) {
  if (threadIdx.x == 0 && blockIdx.x == 0) {
    unsigned npt = 0;
    for (int b = 0; b < BN; ++b) npt += acc->npos[b];
    float hard = 0.f;
    for (int b = 0; b < BN; ++b) hard += acc->hard[b];
    float npf = (float)npt;
    float box = acc->box_sum / (npf * 4.f);
    float cls = (hard + acc->pos_sum) / npf;
    out[0] = box + cls;
    out[1] = box;
    out[2] = cls;
  }
}

extern "C" void kernel_launch(void* const* d_in, const int* in_sizes, int n_in,
                              void* d_out, int out_size, void* d_ws, size_t ws_size,
                              hipStream_t stream) {
  const float*  labels  = (const float*)d_in[0];
  const float4* poffs   = (const float4*)d_in[1];
  const float4* anchors = (const float4*)d_in[2];
  const float4* gt      = (const float4*)d_in[3];
  int A = in_sizes[2] / 4;  // 100000

  char* ws = (char*)d_ws;
  Accum* acc = (Accum*)ws;
  size_t off_hc = (sizeof(Accum) + 255) & ~(size_t)255;
  unsigned int* ghc = (unsigned int*)(ws + off_hc);
  size_t off_hs = off_hc + (size_t)BN * NB * sizeof(unsigned int);
  float* ghs = (float*)(ws + off_hs);
  size_t off_part = off_hs + (size_t)BN * NB * sizeof(float);
  unsigned long long* partial = (unsigned long long*)(ws + off_part);

  hipMemsetAsync(ws, 0, off_part, stream);  // Accum + both histograms

  int nbx = (A + BLK * MITER - 1) / (BLK * MITER);   // 98
  dim3 mgrid(nbx, BN);
  k_match<<<mgrid, BLK, 0, stream>>>(anchors, gt, partial, A);
  k_match2<<<1, 512, 0, stream>>>(partial, acc, nbx);

  dim3 grid(GX, BN);
  k_main<<<grid, BLK, 0, stream>>>(labels, poffs, anchors, gt, acc, ghc, ghs, A);
  k_sel<<<BN, BLK, 0, stream>>>(acc, ghc, ghs);
  k_final<<<1, 64, 0, stream>>>(acc, (float*)d_out);
}